// Round 19
// baseline (268.511 us; speedup 1.0000x reference)
//
#include <hip/hip_runtime.h>
#include <hip/hip_bf16.h>

#define B_   4
#define N_   4096
#define D_   128
#define PH_  32
#define AH_  256
#define K_   16
#define BN_  (B_*N_)

#define S2_  32
#define SC2_ (N_ / S2_)   // 128 points per split

#define SCALE_ 0.08838834764831845f   // 1/sqrt(128)

typedef __attribute__((ext_vector_type(8))) short short8;
typedef __attribute__((ext_vector_type(4))) float f32x4;

__device__ inline float f4c(const float4& v, int i) {
  return i == 0 ? v.x : i == 1 ? v.y : i == 2 ? v.z : v.w;
}

__device__ inline unsigned short f2bf(float f) {
  unsigned u = __float_as_uint(f);
  unsigned r = u + 0x7fffu + ((u >> 16) & 1u);   // round-to-nearest-even
  return (unsigned short)(r >> 16);
}

// native conversion (RNE; lowers to v_cvt_pk_bf16_f32 when paired)
__device__ inline unsigned short f2bfn(float f) {
  __hip_bfloat16 h = __float2bfloat16(f);
  return *reinterpret_cast<unsigned short*>(&h);
}

__device__ inline float bf2f(unsigned short u) {
  return __uint_as_float((unsigned)u << 16);
}

// ---------------- K_A: knn_sel (blocks 0..2047)  ∪  wshuf (blocks 2048..2063) ----------------
__global__ __launch_bounds__(256) void prep_kernel(
    const float* __restrict__ pos, float* __restrict__ part,
    const float* __restrict__ a_w1, const float* __restrict__ a_w2,
    const float* __restrict__ p_w2,
    const float* __restrict__ Wq, const float* __restrict__ Wk, const float* __restrict__ Wv,
    unsigned short* __restrict__ W1f, unsigned short* __restrict__ W2f,
    unsigned short* __restrict__ p2f,
    unsigned short* __restrict__ Wqf, unsigned short* __restrict__ Wkf,
    unsigned short* __restrict__ Wvf)
{
  const int bx = blockIdx.x;
  const int tid = threadIdx.x;

  if (bx < 2048) {
    // ---- kNN selection: top-16 distances per (query, split), med3 sorted-insert ----
    __shared__ float4 sh[SC2_];
    const int qc = bx >> 5, sp = bx & 31;
    const int q = qc * 256 + tid;
    const int b = q >> 12, i = q & (N_ - 1);
    const float* __restrict__ pb = pos + (size_t)b * N_ * 3;
    const int j0 = sp * SC2_;

    for (int e = tid; e < SC2_; e += 256) {
      const float* src = pb + (size_t)(j0 + e) * 3;
      sh[e] = make_float4(src[0], src[1], src[2], 0.f);
    }
    const float qx = pb[i * 3 + 0], qy = pb[i * 3 + 1], qz = pb[i * 3 + 2];
    __syncthreads();

    float c[16];
    #pragma unroll
    for (int s = 0; s < 16; ++s) c[s] = __int_as_float(0x7f800000);   // +inf

    #pragma unroll 4
    for (int j = 0; j < SC2_; ++j) {
      float4 pt = sh[j];
      float dx = qx - pt.x;
      float dy = qy - pt.y;
      float dz = qz - pt.z;
      float d2 = __fadd_rn(__fadd_rn(__fmul_rn(dx, dx), __fmul_rn(dy, dy)), __fmul_rn(dz, dz));
      #pragma unroll
      for (int s = 15; s >= 1; --s) c[s] = __builtin_amdgcn_fmed3f(c[s - 1], c[s], d2);
      c[0] = fminf(c[0], d2);
    }

    float* dst = part + ((size_t)sp * BN_ + q) * 16;
    #pragma unroll
    for (int s = 0; s < 16; ++s) dst[s] = c[s];
  } else {
    // ---- weight shuffle into bf16 B-fragment layout ----
    const int f = (bx - 2048) * 256 + tid;    // 0..4095
    int lane = f & 63, g = lane >> 4, c = lane & 15;
    {
      int nt = f >> 8, kc = (f >> 6) & 3;           // W1: K=128 (4 kc), N=256 (16 nt)
      unsigned short o[8];
      #pragma unroll
      for (int j = 0; j < 8; ++j)
        o[j] = f2bf(a_w1[(size_t)(32 * kc + 8 * g + j) * 256 + 16 * nt + c]);
      #pragma unroll
      for (int j = 0; j < 8; ++j) W1f[(size_t)f * 8 + j] = o[j];
    }
    {
      int nt = f >> 9, kc = (f >> 6) & 7;           // W2: K=256 (8 kc), N=128 (8 nt); 1/sqrt(128) folded
      unsigned short o[8];
      #pragma unroll
      for (int j = 0; j < 8; ++j)
        o[j] = f2bf(a_w2[(size_t)(32 * kc + 8 * g + j) * 128 + 16 * nt + c] * SCALE_);
      #pragma unroll
      for (int j = 0; j < 8; ++j) W2f[(size_t)f * 8 + j] = o[j];
    }
    if (f < 512) {
      int nt = f >> 6;                               // p_w2: K=32, N=128 (8 nt)
      unsigned short o[8];
      #pragma unroll
      for (int j = 0; j < 8; ++j)
        o[j] = f2bf(p_w2[(size_t)(8 * g + j) * 128 + 16 * nt + c]);
      #pragma unroll
      for (int j = 0; j < 8; ++j) p2f[(size_t)f * 8 + j] = o[j];
    }
    if (f < 2048) {                                  // Wq/Wk/Wv: K=128 (4 kc), N=128 (8 nt)
      int nt = f >> 8, kc = (f >> 6) & 3;
      unsigned short oq[8], ok[8], ov[8];
      #pragma unroll
      for (int j = 0; j < 8; ++j) {
        size_t src = (size_t)(32 * kc + 8 * g + j) * 128 + 16 * nt + c;
        oq[j] = f2bf(Wq[src]);
        ok[j] = f2bf(Wk[src]);
        ov[j] = f2bf(Wv[src]);
      }
      #pragma unroll
      for (int j = 0; j < 8; ++j) {
        Wqf[(size_t)f * 8 + j] = oq[j];
        Wkf[(size_t)f * 8 + j] = ok[j];
        Wvf[(size_t)f * 8 + j] = ov[j];
      }
    }
  }
}

// ---------------- K_B: thresh merge (blocks 0..2047)  ∪  qkv MFMA (blocks 2048..3583) ----------------
__global__ __launch_bounds__(256) void thresh_qkv_kernel(
    const float* __restrict__ part,
    float* __restrict__ d16, int* __restrict__ cnt, int* __restrict__ tcnt,
    const float* __restrict__ x,
    const unsigned short* __restrict__ Wqf, const unsigned short* __restrict__ Wkf,
    const unsigned short* __restrict__ Wvf,
    float* __restrict__ xq, float* __restrict__ xk, float* __restrict__ xv)
{
  const int bx = blockIdx.x;
  const int tid = threadIdx.x;

  if (bx < 2048) {
    // ---- 32-lane-group register merge -> 16th smallest distance; zero counters ----
    const int w = tid >> 6, lane = tid & 63;
    const int gg = lane >> 5, s = lane & 31;
    const int q = bx * 8 + w * 2 + gg;

    float v[16];
    const float* src = part + ((size_t)s * BN_ + q) * 16;
    #pragma unroll
    for (int t = 0; t < 16; ++t) v[t] = src[t];

    float mn = v[0];
    #pragma unroll
    for (int step = 0; step < 16; ++step) {
      mn = v[0];
      mn = fminf(mn, __shfl_xor(mn, 1, 64));
      mn = fminf(mn, __shfl_xor(mn, 2, 64));
      mn = fminf(mn, __shfl_xor(mn, 4, 64));
      mn = fminf(mn, __shfl_xor(mn, 8, 64));
      mn = fminf(mn, __shfl_xor(mn, 16, 64));
      if (step == 15) break;
      unsigned long long bal = __ballot(v[0] == mn);
      unsigned grp = (unsigned)((bal >> (32 * gg)) & 0xffffffffull);
      bool adv = (s == (__ffs(grp) - 1));      // advance exactly one head (multiset semantics)
      #pragma unroll
      for (int t = 0; t < 15; ++t) v[t] = adv ? v[t + 1] : v[t];
      v[15] = adv ? __int_as_float(0x7f800000) : v[15];
    }
    if (s == 0) { d16[q] = mn; cnt[q] = 0; tcnt[q] = 0; }
  } else {
    // ---- q/k/v projections via bf16 MFMA: y -> (matrix, N-half) ----
    const int e = bx - 2048;
    const int y = e % 6, bxx = e / 6;
    const int w = tid >> 6, lane = tid & 63;
    const int g = lane >> 4, c = lane & 15;
    const int r0 = (bxx * 4 + w) * 16;
    const int m = y >> 1, nth = y & 1;

    short8 xa[4];
    const float* xrow = x + (size_t)(r0 + c) * 128;
    #pragma unroll
    for (int kc = 0; kc < 4; ++kc) {
      const int d0 = 32 * kc + 8 * g;
      float4 a4 = *(const float4*)(xrow + d0);
      float4 b4 = *(const float4*)(xrow + d0 + 4);
      #pragma unroll
      for (int j = 0; j < 8; ++j) {
        float vv = j < 4 ? f4c(a4, j) : f4c(b4, j - 4);
        xa[kc][j] = (short)f2bfn(vv);
      }
    }

    const unsigned short* Wm = m == 0 ? Wqf : (m == 1 ? Wkf : Wvf);
    float* outm = m == 0 ? xq : (m == 1 ? xk : xv);
    const f32x4 zero4 = {0.f, 0.f, 0.f, 0.f};

    #pragma unroll
    for (int nt = 0; nt < 4; ++nt) {
      const int ntg = nth * 4 + nt;
      f32x4 acc = zero4;
      #pragma unroll
      for (int kc = 0; kc < 4; ++kc) {
        short8 bf = *(const short8*)(Wm + ((size_t)(ntg * 4 + kc) * 64 + lane) * 8);
        acc = __builtin_amdgcn_mfma_f32_16x16x32_bf16(xa[kc], bf, acc, 0, 0, 0);
      }
      #pragma unroll
      for (int r = 0; r < 4; ++r)
        outm[(size_t)(r0 + 4 * g + r) * 128 + ntg * 16 + c] = acc[r];
    }
  }
}

// ---------------- K_C: emit indices with d < d16 (unordered), collect ties ----------------
__global__ __launch_bounds__(256) void knn_emit_kernel(const float* __restrict__ pos,
                                                       const float* __restrict__ d16,
                                                       int* __restrict__ knn,
                                                       int* __restrict__ cnt,
                                                       int* __restrict__ tcnt,
                                                       int* __restrict__ tied)
{
  __shared__ float4 sh[SC2_];
  const int tid = threadIdx.x;
  const int q = blockIdx.x * 256 + tid;
  const int sp = blockIdx.y;
  const int b = q >> 12, i = q & (N_ - 1);
  const float* __restrict__ pb = pos + (size_t)b * N_ * 3;
  const int j0 = sp * SC2_;

  for (int e = tid; e < SC2_; e += 256) {
    const float* src = pb + (size_t)(j0 + e) * 3;
    sh[e] = make_float4(src[0], src[1], src[2], 0.f);
  }
  const float qx = pb[i * 3 + 0], qy = pb[i * 3 + 1], qz = pb[i * 3 + 2];
  const float thr = d16[q];
  __syncthreads();

  for (int j = 0; j < SC2_; ++j) {
    float4 pt = sh[j];
    float dx = qx - pt.x;
    float dy = qy - pt.y;
    float dz = qz - pt.z;
    float d2 = __fadd_rn(__fadd_rn(__fmul_rn(dx, dx), __fmul_rn(dy, dy)), __fmul_rn(dz, dz));
    if (d2 < thr) {
      int p = atomicAdd(&cnt[q], 1);
      knn[(size_t)q * 16 + p] = j0 + j;
    } else if (d2 == thr) {
      int p = atomicAdd(&tcnt[q], 1);
      if (p < 16) tied[(size_t)q * 16 + p] = j0 + j;
    }
  }
}

// ---------------- K_D: sort ties by index, fill remaining slots ----------------
__global__ __launch_bounds__(256) void knn_fix_kernel(const int* __restrict__ cnt,
                                                      const int* __restrict__ tcnt,
                                                      const int* __restrict__ tied,
                                                      int* __restrict__ knn)
{
  const int q = blockIdx.x * 256 + threadIdx.x;
  const int c_lt = cnt[q];
  int tn = tcnt[q]; if (tn > 16) tn = 16;

  int a[16];
  #pragma unroll
  for (int s = 0; s < 16; ++s) a[s] = (s < tn) ? tied[(size_t)q * 16 + s] : 0x7fffffff;

  #pragma unroll
  for (int pass = 0; pass < 15; ++pass) {
    #pragma unroll
    for (int s = 0; s < 15; ++s) {
      int lo = min(a[s], a[s + 1]);
      int hi = max(a[s], a[s + 1]);
      a[s] = lo; a[s + 1] = hi;
    }
  }

  const int need = 16 - c_lt;
  #pragma unroll
  for (int s = 0; s < 16; ++s)
    if (s < need) knn[(size_t)q * 16 + c_lt + s] = a[s];
}

// ---------------- K_E: fused MLP, TWO points per wave (B-fragment sharing) ----------------
// Each wave owns points p0,p0+1: every W1f/W2f B-fragment load feeds 2 MFMAs, halving
// weight L2 traffic (the dominant stall per R15/R16 analysis). ~216 unified regs ->
// 2 waves/SIMD; the 2 independent point-streams supply intra-wave ILP instead.
__global__ __launch_bounds__(256, 2) void fused_mlp_kernel(
    const float* __restrict__ pos,
    const float* __restrict__ xq, const float* __restrict__ xk, const float* __restrict__ xv,
    const int* __restrict__ knn,
    const float* __restrict__ p_w1, const float* __restrict__ p_b1,
    const unsigned short* __restrict__ p2f, const float* __restrict__ p_b2,
    const unsigned short* __restrict__ W1f, const unsigned short* __restrict__ W2f,
    const float* __restrict__ a_b1, const float* __restrict__ a_b2,
    float* __restrict__ out)
{
  __shared__ unsigned short tile[4][2][16][136];   // per-wave, per-point: pe then T1

  const int w = threadIdx.x >> 6, lane = threadIdx.x & 63;
  const int g = lane >> 4, c = lane & 15;
  const size_t p0 = (size_t)blockIdx.x * 8 + (size_t)w * 2;
  const int b = (int)(p0 >> 12);        // p0 even, batch stride 4096 even -> p0,p0+1 same batch

  int idx_r[2], idx4[2][4];
  #pragma unroll
  for (int t = 0; t < 2; ++t) {
    idx_r[t] = knn[(p0 + t) * 16 + c];
    #pragma unroll
    for (int r = 0; r < 4; ++r) idx4[t][r] = knn[(p0 + t) * 16 + 4 * g + r];
  }

  // EARLY gathers for BOTH points (v: 64 scattered f32; k: 16 float4)
  const float* vb = xv + (size_t)b * N_ * 128;
  float vreg[2][8][4];
  #pragma unroll
  for (int t = 0; t < 2; ++t)
    #pragma unroll
    for (int r = 0; r < 4; ++r) {
      const float* vrow = vb + (size_t)idx4[t][r] * 128;
      #pragma unroll
      for (int nt = 0; nt < 8; ++nt) vreg[t][nt][r] = vrow[nt * 16 + c];
    }

  float4 kreg[2][8];
  #pragma unroll
  for (int t = 0; t < 2; ++t) {
    const float* kb = xk + ((size_t)b * N_ + idx_r[t]) * 128;
    #pragma unroll
    for (int kc = 0; kc < 4; ++kc) {
      kreg[t][2 * kc]     = *(const float4*)(kb + 32 * kc + 8 * g);
      kreg[t][2 * kc + 1] = *(const float4*)(kb + 32 * kc + 8 * g + 4);
    }
  }

  const f32x4 zero4 = {0.f, 0.f, 0.f, 0.f};
  short8 ha[2][4];
  unsigned vpe_pk[2][8][2];

  #pragma unroll
  for (int t = 0; t < 2; ++t) {
    const size_t p = p0 + t;
    const float qx = pos[p * 3 + 0], qy = pos[p * 3 + 1], qz = pos[p * 3 + 2];
    const float* pn = pos + ((size_t)b * N_ + idx_r[t]) * 3;
    const float rx = qx - pn[0], ry = qy - pn[1], rz = qz - pn[2];

    // hidden A-frag
    short8 hid;
    #pragma unroll
    for (int j = 0; j < 8; ++j) {
      int hh = 8 * g + j;
      float a = p_b1[hh];
      a = fmaf(rx, p_w1[0 * PH_ + hh], a);
      a = fmaf(ry, p_w1[1 * PH_ + hh], a);
      a = fmaf(rz, p_w1[2 * PH_ + hh], a);
      a = fmaxf(a, 0.f);
      hid[j] = (short)f2bfn(a);
    }

    // pe = hidden @ p_w2 + p_b2 (C layout)
    f32x4 pe8[8];
    #pragma unroll
    for (int nt = 0; nt < 8; ++nt) {
      short8 bf = *(const short8*)(p2f + ((size_t)nt * 64 + lane) * 8);
      pe8[nt] = __builtin_amdgcn_mfma_f32_16x16x32_bf16(hid, bf, zero4, 0, 0, 0);
    }
    #pragma unroll
    for (int nt = 0; nt < 8; ++nt) {
      float b2v = p_b2[nt * 16 + c];
      #pragma unroll
      for (int r = 0; r < 4; ++r) {
        pe8[nt][r] += b2v;
        tile[w][t][g * 4 + r][nt * 16 + c] = f2bfn(pe8[nt][r]);
      }
    }

    // H A-frags
    const float* qb = xq + p * 128;
    #pragma unroll
    for (int kc = 0; kc < 4; ++kc) {
      const int d0 = 32 * kc + 8 * g;
      float4 q4a = *(const float4*)(qb + d0);
      float4 q4b = *(const float4*)(qb + d0 + 4);
      short8 pv = *(const short8*)&tile[w][t][c][d0];
      #pragma unroll
      for (int j = 0; j < 8; ++j) {
        float qv = j < 4 ? f4c(q4a, j) : f4c(q4b, j - 4);
        float kv = j < 4 ? f4c(kreg[t][2 * kc], j) : f4c(kreg[t][2 * kc + 1], j - 4);
        float h = qv - kv + bf2f((unsigned short)pv[j]);
        ha[t][kc][j] = (short)f2bfn(h);
      }
    }

    // vpe = v + pe packed to bf16 pairs
    #pragma unroll
    for (int nt = 0; nt < 8; ++nt) {
      unsigned short e0 = f2bfn(pe8[nt][0] + vreg[t][nt][0]);
      unsigned short e1 = f2bfn(pe8[nt][1] + vreg[t][nt][1]);
      unsigned short e2 = f2bfn(pe8[nt][2] + vreg[t][nt][2]);
      unsigned short e3 = f2bfn(pe8[nt][3] + vreg[t][nt][3]);
      vpe_pk[t][nt][0] = (unsigned)e0 | ((unsigned)e1 << 16);
      vpe_pk[t][nt][1] = (unsigned)e2 | ((unsigned)e3 << 16);
    }
  }

  // attn MLP: quarter-interleaved GEMM1 -> GEMM2, each B-frag serves both points
  f32x4 acc2[2][8];
  #pragma unroll
  for (int t = 0; t < 2; ++t)
    #pragma unroll
    for (int i = 0; i < 8; ++i) acc2[t][i] = zero4;

  #pragma unroll
  for (int h = 0; h < 2; ++h) {
    #pragma unroll
    for (int qq = 0; qq < 2; ++qq) {
      f32x4 acc1[2][4];
      #pragma unroll
      for (int t = 0; t < 2; ++t)
        #pragma unroll
        for (int i = 0; i < 4; ++i) acc1[t][i] = zero4;

      #pragma unroll
      for (int ntl = 0; ntl < 4; ++ntl) {
        const unsigned short* wb = W1f + (size_t)(h * 8 + qq * 4 + ntl) * 2048 + (size_t)lane * 8;
        #pragma unroll
        for (int kc = 0; kc < 4; ++kc) {
          short8 bf = *(const short8*)(wb + (size_t)kc * 512);
          acc1[0][ntl] = __builtin_amdgcn_mfma_f32_16x16x32_bf16(ha[0][kc], bf, acc1[0][ntl], 0, 0, 0);
          acc1[1][ntl] = __builtin_amdgcn_mfma_f32_16x16x32_bf16(ha[1][kc], bf, acc1[1][ntl], 0, 0, 0);
        }
      }
      #pragma unroll
      for (int ntl = 0; ntl < 4; ++ntl) {
        float b1v = a_b1[(h * 8 + qq * 4 + ntl) * 16 + c];
        #pragma unroll
        for (int t = 0; t < 2; ++t) {
          #pragma unroll
          for (int r = 0; r < 4; ++r) {
            float vv = acc1[t][ntl][r] + b1v;
            vv = fmaxf(vv, 0.f);
            tile[w][t][g * 4 + r][(qq * 4 + ntl) * 16 + c] = f2bfn(vv);
          }
        }
      }
      #pragma unroll
      for (int k2 = 0; k2 < 2; ++k2) {
        const int kc2 = qq * 2 + k2;
        short8 a2A = *(const short8*)&tile[w][0][c][kc2 * 32 + g * 8];
        short8 a2B = *(const short8*)&tile[w][1][c][kc2 * 32 + g * 8];
        const unsigned short* w2b = W2f + (size_t)(h * 4 + kc2) * 512 + (size_t)lane * 8;
        #pragma unroll
        for (int nt2 = 0; nt2 < 8; ++nt2) {
          short8 b2f = *(const short8*)(w2b + (size_t)nt2 * 4096);
          acc2[0][nt2] = __builtin_amdgcn_mfma_f32_16x16x32_bf16(a2A, b2f, acc2[0][nt2], 0, 0, 0);
          acc2[1][nt2] = __builtin_amdgcn_mfma_f32_16x16x32_bf16(a2B, b2f, acc2[1][nt2], 0, 0, 0);
        }
      }
    }
  }

  // epilogue per point: scaled bias, softmax over 16 rows, aggregate with vpe
  #pragma unroll
  for (int t = 0; t < 2; ++t) {
    const size_t p = p0 + t;
    #pragma unroll
    for (int nt2 = 0; nt2 < 8; ++nt2) {
      float b2v = a_b2[nt2 * 16 + c] * SCALE_;
      float l0 = acc2[t][nt2][0] + b2v;
      float l1 = acc2[t][nt2][1] + b2v;
      float l2 = acc2[t][nt2][2] + b2v;
      float l3 = acc2[t][nt2][3] + b2v;
      float mx = fmaxf(fmaxf(l0, l1), fmaxf(l2, l3));
      mx = fmaxf(mx, __shfl_xor(mx, 16, 64));
      mx = fmaxf(mx, __shfl_xor(mx, 32, 64));
      float e0 = __expf(l0 - mx);
      float e1 = __expf(l1 - mx);
      float e2 = __expf(l2 - mx);
      float e3 = __expf(l3 - mx);
      float s = e0 + e1 + e2 + e3;
      s += __shfl_xor(s, 16, 64);
      s += __shfl_xor(s, 32, 64);
      float inv = 1.f / s;
      float v0 = bf2f((unsigned short)(vpe_pk[t][nt2][0] & 0xffff));
      float v1 = bf2f((unsigned short)(vpe_pk[t][nt2][0] >> 16));
      float v2 = bf2f((unsigned short)(vpe_pk[t][nt2][1] & 0xffff));
      float v3 = bf2f((unsigned short)(vpe_pk[t][nt2][1] >> 16));
      float ac = (e0 * v0 + e1 * v1 + e2 * v2 + e3 * v3) * inv;
      ac += __shfl_xor(ac, 16, 64);
      ac += __shfl_xor(ac, 32, 64);
      if (g == 0) out[p * 128 + nt2 * 16 + c] = ac;
    }
  }
}

extern "C" void kernel_launch(void* const* d_in, const int* in_sizes, int n_in,
                              void* d_out, int out_size, void* d_ws, size_t ws_size,
                              hipStream_t stream)
{
  const float* x    = (const float*)d_in[0];
  const float* pos  = (const float*)d_in[1];
  const float* Wq   = (const float*)d_in[2];
  const float* Wk   = (const float*)d_in[3];
  const float* Wv   = (const float*)d_in[4];
  const float* p_w1 = (const float*)d_in[5];
  const float* p_b1 = (const float*)d_in[6];
  const float* p_w2 = (const float*)d_in[7];
  const float* p_b2 = (const float*)d_in[8];
  const float* a_w1 = (const float*)d_in[9];
  const float* a_b1 = (const float*)d_in[10];
  const float* a_w2 = (const float*)d_in[11];
  const float* a_b2 = (const float*)d_in[12];
  float* out = (float*)d_out;

  float* xq = (float*)d_ws;                                         // BN*128 f32
  float* xk = xq + (size_t)BN_ * 128;
  float* xv = xk + (size_t)BN_ * 128;
  int*   knn = (int*)(xv + (size_t)BN_ * 128);                      // BN*16 i32
  unsigned short* W1f = (unsigned short*)(knn + (size_t)BN_ * 16);  // 32768 bf16
  unsigned short* W2f = W1f + 32768;                                // 32768 bf16
  unsigned short* p2f = W2f + 32768;                                // 4096 bf16
  unsigned short* Wqf = p2f + 4096;                                 // 16384 bf16
  unsigned short* Wkf = Wqf + 16384;                                // 16384 bf16
  unsigned short* Wvf = Wkf + 16384;                                // 16384 bf16
  float* part = (float*)(Wvf + 16384);                              // S2*BN*16 f32 (33.5 MB)
  float* d16  = part + (size_t)S2_ * BN_ * 16;                      // BN f32
  int* cnt    = (int*)(d16 + BN_);                                  // BN
  int* tcnt   = cnt + BN_;                                          // BN
  int* tied   = tcnt + BN_;                                         // BN*16

  prep_kernel<<<2064, 256, 0, stream>>>(pos, part, a_w1, a_w2, p_w2, Wq, Wk, Wv,
                                        W1f, W2f, p2f, Wqf, Wkf, Wvf);
  thresh_qkv_kernel<<<3584, 256, 0, stream>>>(part, d16, cnt, tcnt,
                                              x, Wqf, Wkf, Wvf, xq, xk, xv);
  knn_emit_kernel<<<dim3(BN_ / 256, S2_), 256, 0, stream>>>(pos, d16, knn, cnt, tcnt, tied);
  knn_fix_kernel<<<BN_ / 256, 256, 0, stream>>>(cnt, tcnt, tied, knn);
  fused_mlp_kernel<<<BN_ / 8, 256, 0, stream>>>(pos, xq, xk, xv, knn,
                                                p_w1, p_b1, p2f, p_b2,
                                                W1f, W2f, a_b1, a_b2, out);
}

// Round 20
// 226.880 us; speedup vs baseline: 1.1835x; 1.1835x over previous
//
#include <hip/hip_runtime.h>
#include <hip/hip_bf16.h>

#define B_   4
#define N_   4096
#define D_   128
#define PH_  32
#define AH_  256
#define K_   16
#define BN_  (B_*N_)

#define S2_  32
#define SC2_ (N_ / S2_)   // 128 points per split

#define SCALE_ 0.08838834764831845f   // 1/sqrt(128)

typedef __attribute__((ext_vector_type(8))) short short8;
typedef __attribute__((ext_vector_type(4))) float f32x4;

__device__ inline float f4c(const float4& v, int i) {
  return i == 0 ? v.x : i == 1 ? v.y : i == 2 ? v.z : v.w;
}

__device__ inline unsigned short f2bf(float f) {
  unsigned u = __float_as_uint(f);
  unsigned r = u + 0x7fffu + ((u >> 16) & 1u);   // round-to-nearest-even
  return (unsigned short)(r >> 16);
}

// native conversion (RNE; lowers to v_cvt_pk_bf16_f32 when paired)
__device__ inline unsigned short f2bfn(float f) {
  __hip_bfloat16 h = __float2bfloat16(f);
  return *reinterpret_cast<unsigned short*>(&h);
}

__device__ inline float bf2f(unsigned short u) {
  return __uint_as_float((unsigned)u << 16);
}

// ---------------- K_A: knn_sel (blocks 0..2047)  ∪  wshuf (blocks 2048..2063) ----------------
__global__ __launch_bounds__(256) void prep_kernel(
    const float* __restrict__ pos, float* __restrict__ part,
    const float* __restrict__ a_w1, const float* __restrict__ a_w2,
    const float* __restrict__ p_w2,
    const float* __restrict__ Wq, const float* __restrict__ Wk, const float* __restrict__ Wv,
    unsigned short* __restrict__ W1f, unsigned short* __restrict__ W2f,
    unsigned short* __restrict__ p2f,
    unsigned short* __restrict__ Wqf, unsigned short* __restrict__ Wkf,
    unsigned short* __restrict__ Wvf)
{
  const int bx = blockIdx.x;
  const int tid = threadIdx.x;

  if (bx < 2048) {
    // ---- kNN selection: top-16 distances per (query, split), med3 sorted-insert ----
    __shared__ float4 sh[SC2_];
    const int qc = bx >> 5, sp = bx & 31;
    const int q = qc * 256 + tid;
    const int b = q >> 12, i = q & (N_ - 1);
    const float* __restrict__ pb = pos + (size_t)b * N_ * 3;
    const int j0 = sp * SC2_;

    for (int e = tid; e < SC2_; e += 256) {
      const float* src = pb + (size_t)(j0 + e) * 3;
      sh[e] = make_float4(src[0], src[1], src[2], 0.f);
    }
    const float qx = pb[i * 3 + 0], qy = pb[i * 3 + 1], qz = pb[i * 3 + 2];
    __syncthreads();

    float c[16];
    #pragma unroll
    for (int s = 0; s < 16; ++s) c[s] = __int_as_float(0x7f800000);   // +inf

    #pragma unroll 4
    for (int j = 0; j < SC2_; ++j) {
      float4 pt = sh[j];
      float dx = qx - pt.x;
      float dy = qy - pt.y;
      float dz = qz - pt.z;
      float d2 = __fadd_rn(__fadd_rn(__fmul_rn(dx, dx), __fmul_rn(dy, dy)), __fmul_rn(dz, dz));
      #pragma unroll
      for (int s = 15; s >= 1; --s) c[s] = __builtin_amdgcn_fmed3f(c[s - 1], c[s], d2);
      c[0] = fminf(c[0], d2);
    }

    float* dst = part + ((size_t)sp * BN_ + q) * 16;
    #pragma unroll
    for (int s = 0; s < 16; ++s) dst[s] = c[s];
  } else {
    // ---- weight shuffle into bf16 B-fragment layout ----
    const int f = (bx - 2048) * 256 + tid;    // 0..4095
    int lane = f & 63, g = lane >> 4, c = lane & 15;
    {
      int nt = f >> 8, kc = (f >> 6) & 3;           // W1: K=128 (4 kc), N=256 (16 nt)
      unsigned short o[8];
      #pragma unroll
      for (int j = 0; j < 8; ++j)
        o[j] = f2bf(a_w1[(size_t)(32 * kc + 8 * g + j) * 256 + 16 * nt + c]);
      #pragma unroll
      for (int j = 0; j < 8; ++j) W1f[(size_t)f * 8 + j] = o[j];
    }
    {
      int nt = f >> 9, kc = (f >> 6) & 7;           // W2: K=256 (8 kc), N=128 (8 nt); 1/sqrt(128) folded
      unsigned short o[8];
      #pragma unroll
      for (int j = 0; j < 8; ++j)
        o[j] = f2bf(a_w2[(size_t)(32 * kc + 8 * g + j) * 128 + 16 * nt + c] * SCALE_);
      #pragma unroll
      for (int j = 0; j < 8; ++j) W2f[(size_t)f * 8 + j] = o[j];
    }
    if (f < 512) {
      int nt = f >> 6;                               // p_w2: K=32, N=128 (8 nt)
      unsigned short o[8];
      #pragma unroll
      for (int j = 0; j < 8; ++j)
        o[j] = f2bf(p_w2[(size_t)(8 * g + j) * 128 + 16 * nt + c]);
      #pragma unroll
      for (int j = 0; j < 8; ++j) p2f[(size_t)f * 8 + j] = o[j];
    }
    if (f < 2048) {                                  // Wq/Wk/Wv: K=128 (4 kc), N=128 (8 nt)
      int nt = f >> 8, kc = (f >> 6) & 3;
      unsigned short oq[8], ok[8], ov[8];
      #pragma unroll
      for (int j = 0; j < 8; ++j) {
        size_t src = (size_t)(32 * kc + 8 * g + j) * 128 + 16 * nt + c;
        oq[j] = f2bf(Wq[src]);
        ok[j] = f2bf(Wk[src]);
        ov[j] = f2bf(Wv[src]);
      }
      #pragma unroll
      for (int j = 0; j < 8; ++j) {
        Wqf[(size_t)f * 8 + j] = oq[j];
        Wkf[(size_t)f * 8 + j] = ok[j];
        Wvf[(size_t)f * 8 + j] = ov[j];
      }
    }
  }
}

// ---------------- K_B: thresh merge (blocks 0..2047)  ∪  qkv MFMA (blocks 2048..3583) ----------------
__global__ __launch_bounds__(256) void thresh_qkv_kernel(
    const float* __restrict__ part,
    float* __restrict__ d16, int* __restrict__ cnt, int* __restrict__ tcnt,
    const float* __restrict__ x,
    const unsigned short* __restrict__ Wqf, const unsigned short* __restrict__ Wkf,
    const unsigned short* __restrict__ Wvf,
    float* __restrict__ xq, float* __restrict__ xk, float* __restrict__ xv)
{
  const int bx = blockIdx.x;
  const int tid = threadIdx.x;

  if (bx < 2048) {
    // ---- 32-lane-group register merge -> 16th smallest distance; zero counters ----
    const int w = tid >> 6, lane = tid & 63;
    const int gg = lane >> 5, s = lane & 31;
    const int q = bx * 8 + w * 2 + gg;

    float v[16];
    const float* src = part + ((size_t)s * BN_ + q) * 16;
    #pragma unroll
    for (int t = 0; t < 16; ++t) v[t] = src[t];

    float mn = v[0];
    #pragma unroll
    for (int step = 0; step < 16; ++step) {
      mn = v[0];
      mn = fminf(mn, __shfl_xor(mn, 1, 64));
      mn = fminf(mn, __shfl_xor(mn, 2, 64));
      mn = fminf(mn, __shfl_xor(mn, 4, 64));
      mn = fminf(mn, __shfl_xor(mn, 8, 64));
      mn = fminf(mn, __shfl_xor(mn, 16, 64));
      if (step == 15) break;
      unsigned long long bal = __ballot(v[0] == mn);
      unsigned grp = (unsigned)((bal >> (32 * gg)) & 0xffffffffull);
      bool adv = (s == (__ffs(grp) - 1));      // advance exactly one head (multiset semantics)
      #pragma unroll
      for (int t = 0; t < 15; ++t) v[t] = adv ? v[t + 1] : v[t];
      v[15] = adv ? __int_as_float(0x7f800000) : v[15];
    }
    if (s == 0) { d16[q] = mn; cnt[q] = 0; tcnt[q] = 0; }
  } else {
    // ---- q/k/v projections via bf16 MFMA: y -> (matrix, N-half) ----
    const int e = bx - 2048;
    const int y = e % 6, bxx = e / 6;
    const int w = tid >> 6, lane = tid & 63;
    const int g = lane >> 4, c = lane & 15;
    const int r0 = (bxx * 4 + w) * 16;
    const int m = y >> 1, nth = y & 1;

    short8 xa[4];
    const float* xrow = x + (size_t)(r0 + c) * 128;
    #pragma unroll
    for (int kc = 0; kc < 4; ++kc) {
      const int d0 = 32 * kc + 8 * g;
      float4 a4 = *(const float4*)(xrow + d0);
      float4 b4 = *(const float4*)(xrow + d0 + 4);
      #pragma unroll
      for (int j = 0; j < 8; ++j) {
        float vv = j < 4 ? f4c(a4, j) : f4c(b4, j - 4);
        xa[kc][j] = (short)f2bfn(vv);
      }
    }

    const unsigned short* Wm = m == 0 ? Wqf : (m == 1 ? Wkf : Wvf);
    float* outm = m == 0 ? xq : (m == 1 ? xk : xv);
    const f32x4 zero4 = {0.f, 0.f, 0.f, 0.f};

    #pragma unroll
    for (int nt = 0; nt < 4; ++nt) {
      const int ntg = nth * 4 + nt;
      f32x4 acc = zero4;
      #pragma unroll
      for (int kc = 0; kc < 4; ++kc) {
        short8 bf = *(const short8*)(Wm + ((size_t)(ntg * 4 + kc) * 64 + lane) * 8);
        acc = __builtin_amdgcn_mfma_f32_16x16x32_bf16(xa[kc], bf, acc, 0, 0, 0);
      }
      #pragma unroll
      for (int r = 0; r < 4; ++r)
        outm[(size_t)(r0 + 4 * g + r) * 128 + ntg * 16 + c] = acc[r];
    }
  }
}

// ---------------- K_C: emit indices with d < d16 (unordered), collect ties ----------------
__global__ __launch_bounds__(256) void knn_emit_kernel(const float* __restrict__ pos,
                                                       const float* __restrict__ d16,
                                                       int* __restrict__ knn,
                                                       int* __restrict__ cnt,
                                                       int* __restrict__ tcnt,
                                                       int* __restrict__ tied)
{
  __shared__ float4 sh[SC2_];
  const int tid = threadIdx.x;
  const int q = blockIdx.x * 256 + tid;
  const int sp = blockIdx.y;
  const int b = q >> 12, i = q & (N_ - 1);
  const float* __restrict__ pb = pos + (size_t)b * N_ * 3;
  const int j0 = sp * SC2_;

  for (int e = tid; e < SC2_; e += 256) {
    const float* src = pb + (size_t)(j0 + e) * 3;
    sh[e] = make_float4(src[0], src[1], src[2], 0.f);
  }
  const float qx = pb[i * 3 + 0], qy = pb[i * 3 + 1], qz = pb[i * 3 + 2];
  const float thr = d16[q];
  __syncthreads();

  for (int j = 0; j < SC2_; ++j) {
    float4 pt = sh[j];
    float dx = qx - pt.x;
    float dy = qy - pt.y;
    float dz = qz - pt.z;
    float d2 = __fadd_rn(__fadd_rn(__fmul_rn(dx, dx), __fmul_rn(dy, dy)), __fmul_rn(dz, dz));
    if (d2 < thr) {
      int p = atomicAdd(&cnt[q], 1);
      knn[(size_t)q * 16 + p] = j0 + j;
    } else if (d2 == thr) {
      int p = atomicAdd(&tcnt[q], 1);
      if (p < 16) tied[(size_t)q * 16 + p] = j0 + j;
    }
  }
}

// ---------------- K_D: sort ties by index, fill remaining slots ----------------
__global__ __launch_bounds__(256) void knn_fix_kernel(const int* __restrict__ cnt,
                                                      const int* __restrict__ tcnt,
                                                      const int* __restrict__ tied,
                                                      int* __restrict__ knn)
{
  const int q = blockIdx.x * 256 + threadIdx.x;
  const int c_lt = cnt[q];
  int tn = tcnt[q]; if (tn > 16) tn = 16;

  int a[16];
  #pragma unroll
  for (int s = 0; s < 16; ++s) a[s] = (s < tn) ? tied[(size_t)q * 16 + s] : 0x7fffffff;

  #pragma unroll
  for (int pass = 0; pass < 15; ++pass) {
    #pragma unroll
    for (int s = 0; s < 15; ++s) {
      int lo = min(a[s], a[s + 1]);
      int hi = max(a[s], a[s + 1]);
      a[s] = lo; a[s + 1] = hi;
    }
  }

  const int need = 16 - c_lt;
  #pragma unroll
  for (int s = 0; s < 16; ++s)
    if (s < need) knn[(size_t)q * 16 + c_lt + s] = a[s];
}

// ---------------- K_E: fully fused pos-MLP + attn-MLP + softmax + aggregation ----------------
// Proven-best body (115 µs): one wave = one point; 4 waves/block; bound (256,3);
// EARLY v-gather + EARLY k-gather; pe8 fp32 through H-build; vpe packed after; __expf;
// scale folded into W2f/a_b2. (Bracketed: bound-4 spills; 2-pt/wave loses ILP;
// LDS weight staging and late gathers regress.)
__global__ __launch_bounds__(256, 3) void fused_mlp_kernel(
    const float* __restrict__ pos,
    const float* __restrict__ xq, const float* __restrict__ xk, const float* __restrict__ xv,
    const int* __restrict__ knn,
    const float* __restrict__ p_w1, const float* __restrict__ p_b1,
    const unsigned short* __restrict__ p2f, const float* __restrict__ p_b2,
    const unsigned short* __restrict__ W1f, const unsigned short* __restrict__ W2f,
    const float* __restrict__ a_b1, const float* __restrict__ a_b2,
    float* __restrict__ out)
{
  __shared__ unsigned short tile[4][16][136];   // per-wave: pe (bf16), then reused for T1

  const int w = threadIdx.x >> 6, lane = threadIdx.x & 63;
  const int g = lane >> 4, c = lane & 15;
  const size_t p = (size_t)blockIdx.x * 4 + w;
  const int b = (int)(p >> 12);

  const int idx_r = knn[p * 16 + c];          // A-frag row for this lane
  int idx4[4];
  #pragma unroll
  for (int r = 0; r < 4; ++r) idx4[r] = knn[p * 16 + 4 * g + r];   // C-layout rows

  // EARLY v-gather: issue the 32 scattered loads now; consumed after the H-build.
  const float* vb = xv + (size_t)b * N_ * 128;
  float vreg[8][4];
  #pragma unroll
  for (int r = 0; r < 4; ++r) {
    const float* vrow = vb + (size_t)idx4[r] * 128;
    #pragma unroll
    for (int nt = 0; nt < 8; ++nt) vreg[nt][r] = vrow[nt * 16 + c];
  }

  // EARLY k-row gather (idx_r-dependent): 8 float4, consumed in the H-build.
  const float* kb = xk + ((size_t)b * N_ + idx_r) * 128;
  float4 kreg[8];
  #pragma unroll
  for (int kc = 0; kc < 4; ++kc) {
    kreg[2 * kc]     = *(const float4*)(kb + 32 * kc + 8 * g);
    kreg[2 * kc + 1] = *(const float4*)(kb + 32 * kc + 8 * g + 4);
  }

  const float qx = pos[p * 3 + 0], qy = pos[p * 3 + 1], qz = pos[p * 3 + 2];
  const float* pn = pos + ((size_t)b * N_ + idx_r) * 3;
  const float rx = qx - pn[0], ry = qy - pn[1], rz = qz - pn[2];

  // hidden A-frag: lane holds hidden[row=c][hh=8g+j]
  short8 hid;
  #pragma unroll
  for (int j = 0; j < 8; ++j) {
    int hh = 8 * g + j;
    float a = p_b1[hh];
    a = fmaf(rx, p_w1[0 * PH_ + hh], a);
    a = fmaf(ry, p_w1[1 * PH_ + hh], a);
    a = fmaf(rz, p_w1[2 * PH_ + hh], a);
    a = fmaxf(a, 0.f);
    hid[j] = (short)f2bfn(a);
  }

  // pe = hidden @ p_w2 + p_b2 : 8 MFMA, C layout (lane holds pe[4g+r][16nt+c])
  f32x4 pe8[8];
  const f32x4 zero4 = {0.f, 0.f, 0.f, 0.f};
  #pragma unroll
  for (int nt = 0; nt < 8; ++nt) {
    short8 bf = *(const short8*)(p2f + ((size_t)nt * 64 + lane) * 8);
    pe8[nt] = __builtin_amdgcn_mfma_f32_16x16x32_bf16(hid, bf, zero4, 0, 0, 0);
  }
  // bias + stage bf16 pe to LDS (for the A-layout transpose)
  #pragma unroll
  for (int nt = 0; nt < 8; ++nt) {
    float b2v = p_b2[nt * 16 + c];
    #pragma unroll
    for (int r = 0; r < 4; ++r) {
      pe8[nt][r] += b2v;
      tile[w][g * 4 + r][nt * 16 + c] = f2bfn(pe8[nt][r]);
    }
  }

  // H A-frags: lane holds H[row=c][d = 32kc+8g+j] = q[d] - k[idx_r][d] + pe
  short8 ha[4];
  const float* qb = xq + p * 128;
  #pragma unroll
  for (int kc = 0; kc < 4; ++kc) {
    const int d0 = 32 * kc + 8 * g;
    float4 q4a = *(const float4*)(qb + d0);
    float4 q4b = *(const float4*)(qb + d0 + 4);
    short8 pv = *(const short8*)&tile[w][c][d0];
    #pragma unroll
    for (int j = 0; j < 8; ++j) {
      float qv = j < 4 ? f4c(q4a, j) : f4c(q4b, j - 4);
      float kv = j < 4 ? f4c(kreg[2 * kc], j) : f4c(kreg[2 * kc + 1], j - 4);
      float h = qv - kv + bf2f((unsigned short)pv[j]);
      ha[kc][j] = (short)f2bfn(h);
    }
  }

  // vpe = v + pe packed to bf16 pairs (frees pe8+vreg -> 16 regs for the GEMM phase)
  unsigned vpe_pk[8][2];
  #pragma unroll
  for (int nt = 0; nt < 8; ++nt) {
    unsigned short e0 = f2bfn(pe8[nt][0] + vreg[nt][0]);
    unsigned short e1 = f2bfn(pe8[nt][1] + vreg[nt][1]);
    unsigned short e2 = f2bfn(pe8[nt][2] + vreg[nt][2]);
    unsigned short e3 = f2bfn(pe8[nt][3] + vreg[nt][3]);
    vpe_pk[nt][0] = (unsigned)e0 | ((unsigned)e1 << 16);
    vpe_pk[nt][1] = (unsigned)e2 | ((unsigned)e3 << 16);
  }

  // attn MLP: quarter-interleaved GEMM1 -> GEMM2 (W2f pre-scaled by 1/sqrt(128))
  f32x4 acc2[8];
  #pragma unroll
  for (int i = 0; i < 8; ++i) acc2[i] = zero4;

  #pragma unroll
  for (int h = 0; h < 2; ++h) {
    #pragma unroll
    for (int qq = 0; qq < 2; ++qq) {
      f32x4 acc1[4];
      #pragma unroll
      for (int i = 0; i < 4; ++i) acc1[i] = zero4;

      #pragma unroll
      for (int ntl = 0; ntl < 4; ++ntl) {
        const unsigned short* wb = W1f + (size_t)(h * 8 + qq * 4 + ntl) * 2048 + (size_t)lane * 8;
        #pragma unroll
        for (int kc = 0; kc < 4; ++kc) {
          short8 bf = *(const short8*)(wb + (size_t)kc * 512);
          acc1[ntl] = __builtin_amdgcn_mfma_f32_16x16x32_bf16(ha[kc], bf, acc1[ntl], 0, 0, 0);
        }
      }
      #pragma unroll
      for (int ntl = 0; ntl < 4; ++ntl) {
        float b1v = a_b1[(h * 8 + qq * 4 + ntl) * 16 + c];
        #pragma unroll
        for (int r = 0; r < 4; ++r) {
          float vv = acc1[ntl][r] + b1v;
          vv = fmaxf(vv, 0.f);
          tile[w][g * 4 + r][(qq * 4 + ntl) * 16 + c] = f2bfn(vv);
        }
      }
      #pragma unroll
      for (int k2 = 0; k2 < 2; ++k2) {
        const int kc2 = qq * 2 + k2;
        short8 a2 = *(const short8*)&tile[w][c][kc2 * 32 + g * 8];
        const unsigned short* w2b = W2f + (size_t)(h * 4 + kc2) * 512 + (size_t)lane * 8;
        #pragma unroll
        for (int nt2 = 0; nt2 < 8; ++nt2) {
          short8 b2f = *(const short8*)(w2b + (size_t)nt2 * 4096);
          acc2[nt2] = __builtin_amdgcn_mfma_f32_16x16x32_bf16(a2, b2f, acc2[nt2], 0, 0, 0);
        }
      }
    }
  }

  // epilogue: scaled bias, softmax over the 16 rows (per column), aggregate with vpe
  #pragma unroll
  for (int nt2 = 0; nt2 < 8; ++nt2) {
    float b2v = a_b2[nt2 * 16 + c] * SCALE_;
    float l0 = acc2[nt2][0] + b2v;
    float l1 = acc2[nt2][1] + b2v;
    float l2 = acc2[nt2][2] + b2v;
    float l3 = acc2[nt2][3] + b2v;
    float mx = fmaxf(fmaxf(l0, l1), fmaxf(l2, l3));
    mx = fmaxf(mx, __shfl_xor(mx, 16, 64));
    mx = fmaxf(mx, __shfl_xor(mx, 32, 64));
    float e0 = __expf(l0 - mx);
    float e1 = __expf(l1 - mx);
    float e2 = __expf(l2 - mx);
    float e3 = __expf(l3 - mx);
    float s = e0 + e1 + e2 + e3;
    s += __shfl_xor(s, 16, 64);
    s += __shfl_xor(s, 32, 64);
    float inv = 1.f / s;
    float v0 = bf2f((unsigned short)(vpe_pk[nt2][0] & 0xffff));
    float v1 = bf2f((unsigned short)(vpe_pk[nt2][0] >> 16));
    float v2 = bf2f((unsigned short)(vpe_pk[nt2][1] & 0xffff));
    float v3 = bf2f((unsigned short)(vpe_pk[nt2][1] >> 16));
    float ac = (e0 * v0 + e1 * v1 + e2 * v2 + e3 * v3) * inv;
    ac += __shfl_xor(ac, 16, 64);
    ac += __shfl_xor(ac, 32, 64);
    if (g == 0) out[p * 128 + nt2 * 16 + c] = ac;
  }
}

extern "C" void kernel_launch(void* const* d_in, const int* in_sizes, int n_in,
                              void* d_out, int out_size, void* d_ws, size_t ws_size,
                              hipStream_t stream)
{
  const float* x    = (const float*)d_in[0];
  const float* pos  = (const float*)d_in[1];
  const float* Wq   = (const float*)d_in[2];
  const float* Wk   = (const float*)d_in[3];
  const float* Wv   = (const float*)d_in[4];
  const float* p_w1 = (const float*)d_in[5];
  const float* p_b1 = (const float*)d_in[6];
  const float* p_w2 = (const float*)d_in[7];
  const float* p_b2 = (const float*)d_in[8];
  const float* a_w1 = (const float*)d_in[9];
  const float* a_b1 = (const float*)d_in[10];
  const float* a_w2 = (const float*)d_in[11];
  const float* a_b2 = (const float*)d_in[12];
  float* out = (float*)d_out;

  float* xq = (float*)d_ws;                                         // BN*128 f32
  float* xk = xq + (size_t)BN_ * 128;
  float* xv = xk + (size_t)BN_ * 128;
  int*   knn = (int*)(xv + (size_t)BN_ * 128);                      // BN*16 i32
  unsigned short* W1f = (unsigned short*)(knn + (size_t)BN_ * 16);  // 32768 bf16
  unsigned short* W2f = W1f + 32768;                                // 32768 bf16
  unsigned short* p2f = W2f + 32768;                                // 4096 bf16
  unsigned short* Wqf = p2f + 4096;                                 // 16384 bf16
  unsigned short* Wkf = Wqf + 16384;                                // 16384 bf16
  unsigned short* Wvf = Wkf + 16384;                                // 16384 bf16
  float* part = (float*)(Wvf + 16384);                              // S2*BN*16 f32 (33.5 MB)
  float* d16  = part + (size_t)S2_ * BN_ * 16;                      // BN f32
  int* cnt    = (int*)(d16 + BN_);                                  // BN
  int* tcnt   = cnt + BN_;                                          // BN
  int* tied   = tcnt + BN_;                                         // BN*16

  prep_kernel<<<2064, 256, 0, stream>>>(pos, part, a_w1, a_w2, p_w2, Wq, Wk, Wv,
                                        W1f, W2f, p2f, Wqf, Wkf, Wvf);
  thresh_qkv_kernel<<<3584, 256, 0, stream>>>(part, d16, cnt, tcnt,
                                              x, Wqf, Wkf, Wvf, xq, xk, xv);
  knn_emit_kernel<<<dim3(BN_ / 256, S2_), 256, 0, stream>>>(pos, d16, knn, cnt, tcnt, tied);
  knn_fix_kernel<<<BN_ / 256, 256, 0, stream>>>(cnt, tcnt, tied, knn);
  fused_mlp_kernel<<<BN_ / 4, 256, 0, stream>>>(pos, xq, xk, xv, knn,
                                                p_w1, p_b1, p2f, p_b2,
                                                W1f, W2f, a_b1, a_b2, out);
}